// Round 1
// baseline (79.845 us; speedup 1.0000x reference)
//
#include <hip/hip_runtime.h>

#define BINS 10
#define NB   1024
#define TPB  256

// Packed per-bin accumulator: bits [48:63] = valid count, bits [0:47] = bce sum
// in fixed point with scale 2^20. Per-wave bounds: count <= 4096 (< 2^16),
// sum <= 4096 * ~8 * 2^20 ~= 3.4e10 (<< 2^48) -> no cross-field carry.

__device__ __forceinline__ void ghm_row(float p0, float p1, int t, float w0, float w1,
                                        unsigned long long* hrow)
{
    // softmax over 2 classes (max-subtract, matching jax.nn.softmax)
    float m  = fmaxf(p0, p1);
    float e0 = expf(p0 - m);
    float e1 = expf(p1 - m);
    float s  = e0 + e1;
    float q0 = e0 / s;
    float q1 = e1 / s;
    float t0 = (t == 0) ? 1.0f : 0.0f;
    float t1 = 1.0f - t0;
    float g0 = fabsf(q0 - t0);
    float g1 = fabsf(q1 - t1);
    int b0 = min((int)(g0 * 10.0f), BINS - 1);
    int b1 = min((int)(g1 * 10.0f), BINS - 1);
    // BCE with logits (stable form, matches reference)
    float bce0 = fmaxf(p0, 0.0f) - p0 * t0 + log1pf(expf(-fabsf(p0)));
    float bce1 = fmaxf(p1, 0.0f) - p1 * t1 + log1pf(expf(-fabsf(p1)));
    unsigned long long c0 = (w0 > 0.0f)
        ? ((1ULL << 48) | (unsigned long long)(bce0 * 1048576.0f + 0.5f)) : 0ULL;
    unsigned long long c1 = (w1 > 0.0f)
        ? ((1ULL << 48) | (unsigned long long)(bce1 * 1048576.0f + 0.5f)) : 0ULL;
    if (b0 == b1) {
        unsigned long long cs = c0 + c1;
        if (cs) atomicAdd(&hrow[b0], cs);
    } else {
        if (c0) atomicAdd(&hrow[b0], c0);
        if (c1) atomicAdd(&hrow[b1], c1);
    }
}

__global__ __launch_bounds__(TPB) void ghm_stage1(
    const float* __restrict__ pred, const int* __restrict__ target,
    const float* __restrict__ lw, unsigned long long* __restrict__ partial, int B)
{
    __shared__ unsigned long long h[4][BINS];   // one histogram copy per wave
    if (threadIdx.x < 4 * BINS)
        ((unsigned long long*)h)[threadIdx.x] = 0ULL;
    __syncthreads();

    const int wid = threadIdx.x >> 6;
    unsigned long long* hrow = h[wid];

    const float4* p4 = (const float4*)pred;
    const float4* w4 = (const float4*)lw;
    const int2*   t2 = (const int2*)target;

    const int npairs = B >> 1;
    const int stride = gridDim.x * blockDim.x;
    for (int i = blockIdx.x * blockDim.x + threadIdx.x; i < npairs; i += stride) {
        float4 p = p4[i];
        float4 w = w4[i];
        int2   t = t2[i];
        ghm_row(p.x, p.y, t.x, w.x, w.y, hrow);
        ghm_row(p.z, p.w, t.y, w.z, w.w, hrow);
    }
    // odd-B tail (not hit for this problem's B, kept for generality)
    if ((B & 1) && blockIdx.x == 0 && threadIdx.x == 0) {
        int r = B - 1;
        ghm_row(pred[2 * r], pred[2 * r + 1], target[r], lw[2 * r], lw[2 * r + 1], h[0]);
    }
    __syncthreads();

    // deterministic per-block partial write (no global atomics)
    if (threadIdx.x < BINS) {
        unsigned long long v = h[0][threadIdx.x] + h[1][threadIdx.x]
                             + h[2][threadIdx.x] + h[3][threadIdx.x];
        partial[blockIdx.x * BINS + threadIdx.x] = v;
    }
}

__global__ __launch_bounds__(TPB) void ghm_stage2(
    const unsigned long long* __restrict__ partial, float* __restrict__ out)
{
    double dsum[BINS];
    double dcnt[BINS];
#pragma unroll
    for (int b = 0; b < BINS; ++b) { dsum[b] = 0.0; dcnt[b] = 0.0; }

    for (int i = threadIdx.x; i < NB; i += TPB) {
#pragma unroll
        for (int b = 0; b < BINS; ++b) {
            unsigned long long p = partial[i * BINS + b];
            dcnt[b] += (double)(p >> 48);
            dsum[b] += (double)(p & ((1ULL << 48) - 1)) * (1.0 / 1048576.0);
        }
    }

#pragma unroll
    for (int b = 0; b < BINS; ++b) {
        for (int off = 32; off > 0; off >>= 1) {
            dsum[b] += __shfl_down(dsum[b], off);
            dcnt[b] += __shfl_down(dcnt[b], off);
        }
    }

    __shared__ double ss[4][BINS];
    __shared__ double sc[4][BINS];
    const int wid  = threadIdx.x >> 6;
    const int lane = threadIdx.x & 63;
    if (lane == 0) {
#pragma unroll
        for (int b = 0; b < BINS; ++b) { ss[wid][b] = dsum[b]; sc[wid][b] = dcnt[b]; }
    }
    __syncthreads();

    if (threadIdx.x == 0) {
        double loss = 0.0;
        int n = 0;
        for (int b = 0; b < BINS; ++b) {
            double S = ss[0][b] + ss[1][b] + ss[2][b] + ss[3][b];
            double C = sc[0][b] + sc[1][b] + sc[2][b] + sc[3][b];
            if (C > 0.0) { ++n; loss += S / C; }
        }
        if (n == 0) n = 1;
        out[0] = (float)(loss / (double)n);
    }
}

extern "C" void kernel_launch(void* const* d_in, const int* in_sizes, int n_in,
                              void* d_out, int out_size, void* d_ws, size_t ws_size,
                              hipStream_t stream)
{
    const float* pred   = (const float*)d_in[0];
    const int*   target = (const int*)d_in[1];
    const float* lw     = (const float*)d_in[2];
    const int B = in_sizes[1];

    unsigned long long* partial = (unsigned long long*)d_ws;  // NB*BINS*8 = 80 KB

    ghm_stage1<<<NB, TPB, 0, stream>>>(pred, target, lw, partial, B);
    ghm_stage2<<<1, TPB, 0, stream>>>(partial, (float*)d_out);
}

// Round 2
// 40.531 us; speedup vs baseline: 1.9700x; 1.9700x over previous
//
#include <hip/hip_runtime.h>

#define BINS 10
#define TPB  256
#define NCOPY 8   // one histogram copy per 32-lane half-wave

// Packed per-bin accumulator: bits [48:63] = valid count, bits [0:47] = bce sum
// in fixed point with scale 2^20. Per-copy bounds: count <= 2*8M/... bounded by
// rows/copy ~ 2^13 * 2 (< 2^16); sum <= 2^14 * ~15 * 2^20 < 2^48. No carry.

__device__ __forceinline__ void ghm_row(float p0, float p1, int t, float w0, float w1,
                                        unsigned long long* hrow)
{
    // C=2: softmax == sigmoid, and |q0-t0| == |q1-t1| == g  (q0+q1 = t0+t1 = 1)
    // g = sigmoid(t==0 ? p1-p0 : p0-p1)
    float z = (t == 0) ? (p1 - p0) : (p0 - p1);
    float e = __expf(-z);
    float g = __fdividef(1.0f, 1.0f + e);
    int bin = min((int)(g * 10.0f), BINS - 1);

    // BCE with logits, stable form: max(p,0) - p*t + log1p(exp(-|p|))
    float l0 = __logf(1.0f + __expf(-fabsf(p0)));
    float l1 = __logf(1.0f + __expf(-fabsf(p1)));
    float bce0 = fmaxf(p0, 0.0f) - ((t == 0) ? p0 : 0.0f) + l0;
    float bce1 = fmaxf(p1, 0.0f) - ((t == 1) ? p1 : 0.0f) + l1;

    bool v0 = (w0 > 0.0f);
    bool v1 = (w1 > 0.0f);
    float wsum = (v0 ? bce0 : 0.0f) + (v1 ? bce1 : 0.0f);
    unsigned long long cnt = (unsigned long long)((int)v0 + (int)v1);
    unsigned long long packed = (cnt << 48)
        | (unsigned long long)(unsigned int)(wsum * 1048576.0f + 0.5f);
    if (packed) atomicAdd(&hrow[bin], packed);
}

__global__ __launch_bounds__(TPB) void ghm_stage1(
    const float* __restrict__ pred, const int* __restrict__ target,
    const float* __restrict__ lw, unsigned long long* __restrict__ partial, int B)
{
    __shared__ unsigned long long h[NCOPY][BINS];
    if (threadIdx.x < NCOPY * BINS)
        ((unsigned long long*)h)[threadIdx.x] = 0ULL;
    __syncthreads();

    unsigned long long* hrow = h[threadIdx.x >> 5];

    const float4* p4 = (const float4*)pred;
    const float4* w4 = (const float4*)lw;
    const int2*   t2 = (const int2*)target;

    const int npairs = B >> 1;
    const int stride = gridDim.x * blockDim.x;
    for (int i = blockIdx.x * blockDim.x + threadIdx.x; i < npairs; i += stride) {
        float4 p = p4[i];
        float4 w = w4[i];
        int2   t = t2[i];
        ghm_row(p.x, p.y, t.x, w.x, w.y, hrow);
        ghm_row(p.z, p.w, t.y, w.z, w.w, hrow);
    }
    if ((B & 1) && blockIdx.x == 0 && threadIdx.x == 0) {
        int r = B - 1;
        ghm_row(pred[2 * r], pred[2 * r + 1], target[r], lw[2 * r], lw[2 * r + 1], h[0]);
    }
    __syncthreads();

    if (threadIdx.x < BINS) {
        unsigned long long v = 0;
#pragma unroll
        for (int c = 0; c < NCOPY; ++c) v += h[c][threadIdx.x];
        partial[blockIdx.x * BINS + threadIdx.x] = v;
    }
}

__global__ __launch_bounds__(TPB) void ghm_stage2(
    const unsigned long long* __restrict__ partial, float* __restrict__ out, int nb)
{
    double dsum[BINS];
    double dcnt[BINS];
#pragma unroll
    for (int b = 0; b < BINS; ++b) { dsum[b] = 0.0; dcnt[b] = 0.0; }

    for (int i = threadIdx.x; i < nb; i += TPB) {
#pragma unroll
        for (int b = 0; b < BINS; ++b) {
            unsigned long long p = partial[i * BINS + b];
            dcnt[b] += (double)(p >> 48);
            dsum[b] += (double)(p & ((1ULL << 48) - 1)) * (1.0 / 1048576.0);
        }
    }

#pragma unroll
    for (int b = 0; b < BINS; ++b) {
        for (int off = 32; off > 0; off >>= 1) {
            dsum[b] += __shfl_down(dsum[b], off);
            dcnt[b] += __shfl_down(dcnt[b], off);
        }
    }

    __shared__ double ss[4][BINS];
    __shared__ double sc[4][BINS];
    const int wid  = threadIdx.x >> 6;
    const int lane = threadIdx.x & 63;
    if (lane == 0) {
#pragma unroll
        for (int b = 0; b < BINS; ++b) { ss[wid][b] = dsum[b]; sc[wid][b] = dcnt[b]; }
    }
    __syncthreads();

    if (threadIdx.x == 0) {
        double loss = 0.0;
        int n = 0;
        for (int b = 0; b < BINS; ++b) {
            double S = ss[0][b] + ss[1][b] + ss[2][b] + ss[3][b];
            double C = sc[0][b] + sc[1][b] + sc[2][b] + sc[3][b];
            if (C > 0.0) { ++n; loss += S / C; }
        }
        if (n == 0) n = 1;
        out[0] = (float)(loss / (double)n);
    }
}

extern "C" void kernel_launch(void* const* d_in, const int* in_sizes, int n_in,
                              void* d_out, int out_size, void* d_ws, size_t ws_size,
                              hipStream_t stream)
{
    const float* pred   = (const float*)d_in[0];
    const int*   target = (const int*)d_in[1];
    const float* lw     = (const float*)d_in[2];
    const int B = in_sizes[1];

    // 2048 blocks -> 8 blocks/CU (32 waves/CU). Partials: nb*BINS*8 bytes.
    int nb = 2048;
    size_t need = (size_t)nb * BINS * sizeof(unsigned long long);
    if (ws_size < need) nb = (int)(ws_size / (BINS * sizeof(unsigned long long)));

    unsigned long long* partial = (unsigned long long*)d_ws;

    ghm_stage1<<<nb, TPB, 0, stream>>>(pred, target, lw, partial, B);
    ghm_stage2<<<1, TPB, 0, stream>>>(partial, (float*)d_out, nb);
}